// Round 8
// baseline (754.517 us; speedup 1.0000x reference)
//
#include <hip/hip_runtime.h>

#define N_NODES   100000
#define N_EDGES   1600000
#define D         64
#define N_TARGETS 100
#define N_GRAPHS  512

typedef _Float16 half4 __attribute__((ext_vector_type(4)));

// ---------------- utility ----------------

__global__ void k_zero_i(int* __restrict__ p, int n) {
    int i = blockIdx.x * blockDim.x + threadIdx.x;
    if (i < n) p[i] = 0;
}
__global__ void k_zero_f(float* __restrict__ p, int n) {
    int i = blockIdx.x * blockDim.x + threadIdx.x;
    if (i < n) p[i] = 0.0f;
}

// ---------------- CSR build ----------------

__global__ void k_deg(const int* __restrict__ dst, int* __restrict__ deg) {
    int e = blockIdx.x * blockDim.x + threadIdx.x;
    if (e < N_EDGES) atomicAdd(&deg[dst[e]], 1);
}

__global__ void k_dinv(const int* __restrict__ deg, float* __restrict__ dinv) {
    int i = blockIdx.x * blockDim.x + threadIdx.x;
    if (i < N_NODES) dinv[i] = rsqrtf((float)deg[i] + 1.0f);  // +1 self-loop
}

__global__ void k_scan1(const int* __restrict__ deg, int* __restrict__ base,
                        int* __restrict__ bsum) {
    __shared__ int s[256];
    int t = threadIdx.x, i = blockIdx.x * 256 + t;
    int v = (i < N_NODES) ? deg[i] : 0;
    s[t] = v;
    __syncthreads();
    for (int off = 1; off < 256; off <<= 1) {
        int x = (t >= off) ? s[t - off] : 0;
        __syncthreads();
        s[t] += x;
        __syncthreads();
    }
    if (i < N_NODES) base[i] = s[t] - v;
    if (t == 255) bsum[blockIdx.x] = s[255];
}

__global__ void k_scan2(int* __restrict__ bsum, int nb) {
    __shared__ int s[512];
    int t = threadIdx.x;
    int v = (t < nb) ? bsum[t] : 0;
    s[t] = v;
    __syncthreads();
    for (int off = 1; off < 512; off <<= 1) {
        int x = (t >= off) ? s[t - off] : 0;
        __syncthreads();
        s[t] += x;
        __syncthreads();
    }
    if (t < nb) bsum[t] = s[t] - v;
}

__global__ void k_scan3(int* __restrict__ base, const int* __restrict__ bsum,
                        int* __restrict__ cursor) {
    int i = blockIdx.x * blockDim.x + threadIdx.x;
    if (i < N_NODES) {
        base[i] += bsum[i >> 8];
        cursor[i] = 0;
    }
    if (i == 0) base[N_NODES] = N_EDGES;
}

__global__ void k_fill(const int* __restrict__ src, const int* __restrict__ dst,
                       const int* __restrict__ base, int* __restrict__ cursor,
                       int* __restrict__ esrc) {
    int e = blockIdx.x * blockDim.x + threadIdx.x;
    if (e < N_EDGES) {
        int d = dst[e];
        int pos = base[d] + atomicAdd(&cursor[d], 1);
        esrc[pos] = src[e];
    }
}

// ------ matmul: H16c[c][row][0:16] = fp16( (relu?)X[row] @ W * dinv[row] ) ------
// Output written in 4 feature-chunks of 16 (each chunk = N*32B = 3.2MB, fits
// in a 4MB per-XCD L2 during the pull passes).
__global__ void __launch_bounds__(256)
k_mm(const float* __restrict__ X, const float* __restrict__ W,
     const float* __restrict__ dinv, _Float16* __restrict__ Y16, int relu) {
    __shared__ float Xs[64][68];
    __shared__ float Ws[64][68];
    int tid = threadIdx.x;
    int r0  = blockIdx.x * 64;
    {
        int lr = tid >> 4;
        int lc = (tid & 15) * 4;
#pragma unroll
        for (int i = 0; i < 4; ++i) {
            int row = lr + 16 * i;
            *(float4*)&Ws[row][lc] = *(const float4*)(W + row * 64 + lc);
            int gr = r0 + row;
            if (gr < N_NODES) {
                float4 xv = *(const float4*)(X + (size_t)gr * 64 + lc);
                if (relu) {
                    xv.x = fmaxf(xv.x, 0.0f); xv.y = fmaxf(xv.y, 0.0f);
                    xv.z = fmaxf(xv.z, 0.0f); xv.w = fmaxf(xv.w, 0.0f);
                }
                *(float4*)&Xs[row][lc] = xv;
            }
        }
    }
    __syncthreads();

    int tx = (tid & 15) * 4;
    int ty = (tid >> 4) * 4;
    float acc[4][4] = {{0.f}};

#pragma unroll
    for (int kk = 0; kk < 16; ++kk) {
        float4 a[4], w[4];
#pragma unroll
        for (int r = 0; r < 4; ++r) a[r] = *(float4*)&Xs[ty + r][kk * 4];
#pragma unroll
        for (int k = 0; k < 4; ++k) w[k] = *(float4*)&Ws[kk * 4 + k][tx];
#pragma unroll
        for (int r = 0; r < 4; ++r) {
#pragma unroll
            for (int k = 0; k < 4; ++k) {
                float av = ((const float*)&a[r])[k];
                acc[r][0] = fmaf(av, w[k].x, acc[r][0]);
                acc[r][1] = fmaf(av, w[k].y, acc[r][1]);
                acc[r][2] = fmaf(av, w[k].z, acc[r][2]);
                acc[r][3] = fmaf(av, w[k].w, acc[r][3]);
            }
        }
    }

    int c  = tx >> 4;      // feature chunk
    int cc = tx & 15;      // col within chunk
    _Float16* Hc = Y16 + (size_t)c * N_NODES * 16;
#pragma unroll
    for (int r = 0; r < 4; ++r) {
        int gr = r0 + ty + r;
        if (gr < N_NODES) {
            float di = dinv[gr];
            half4 o;
            o.x = (_Float16)(acc[r][0] * di);
            o.y = (_Float16)(acc[r][1] * di);
            o.z = (_Float16)(acc[r][2] * di);
            o.w = (_Float16)(acc[r][3] * di);
            *(half4*)(Hc + (size_t)gr * 16 + cc) = o;
        }
    }
}

// ---------------- pull aggregation, chunked (L2-resident gather) ----------
// grid = (N/16, 4): blockIdx.y = feature chunk (passes dispatch y-major, so
// all blocks of chunk c run ~together; each 3.2MB chunk is L2-resident).
// Wave = 4 nodes x 16 lanes (lane = feature). No cross-lane reduction needed.
// Edge indices are subgroup-uniform dword loads; gathers are 16-lane x 2B
// (32B/row) from the resident chunk; 4-deep unroll for latency hiding.
__global__ void __launch_bounds__(256)
k_pull_c(const _Float16* __restrict__ H16, const int* __restrict__ esrc,
         const int* __restrict__ base, const float* __restrict__ dinv,
         const float* __restrict__ b, float* __restrict__ AGG) {
    int c = blockIdx.y;
    const _Float16* Hc = H16 + (size_t)c * N_NODES * 16;
    int tid  = threadIdx.x;
    int wv   = tid >> 6;
    int lane = tid & 63;
    int sg   = lane >> 4;        // node slot within wave
    int f    = lane & 15;        // feature within chunk
    int i    = blockIdx.x * 16 + wv * 4 + sg;   // N_NODES/16 = 6250 exact
    int s0 = base[i], s1 = base[i + 1];
    float acc = (float)Hc[(size_t)i * 16 + f];  // self term (pre-scaled)
    int p = s0;
    for (; p + 4 <= s1; p += 4) {
        int e0 = esrc[p];
        int e1 = esrc[p + 1];
        int e2 = esrc[p + 2];
        int e3 = esrc[p + 3];
        float v0 = (float)Hc[(size_t)e0 * 16 + f];
        float v1 = (float)Hc[(size_t)e1 * 16 + f];
        float v2 = (float)Hc[(size_t)e2 * 16 + f];
        float v3 = (float)Hc[(size_t)e3 * 16 + f];
        acc += (v0 + v1) + (v2 + v3);
    }
    for (; p < s1; ++p)
        acc += (float)Hc[(size_t)esrc[p] * 16 + f];
    int col = c * 16 + f;
    AGG[(size_t)i * D + col] = fmaf(acc, dinv[i], b[col]);
}

// ---- segment-sorted pooling: register accumulate, atomic flush on boundary ----
__global__ void __launch_bounds__(256)
k_pool_seg(const float* __restrict__ H, const int* __restrict__ seg,
           float* __restrict__ pooled) {
    int wave = threadIdx.x >> 6;
    int lane = threadIdx.x & 63;
    int n0 = (blockIdx.x * 4 + wave) * 64;
    if (n0 >= N_NODES) return;
    int nEnd = n0 + 64;
    if (nEnd > N_NODES) nEnd = N_NODES;
    int cur = seg[n0];
    float acc = 0.0f;
    for (int n = n0; n < nEnd; ++n) {
        int gsg = seg[n];  // wave-uniform
        if (gsg != cur) {
            atomicAdd(&pooled[(size_t)cur * D + lane], acc);
            acc = 0.0f;
            cur = gsg;
        }
        acc += H[(size_t)n * D + lane];
    }
    atomicAdd(&pooled[(size_t)cur * D + lane], acc);
}

__global__ void k_counts(const int* __restrict__ seg, float* __restrict__ counts) {
    int i = blockIdx.x * blockDim.x + threadIdx.x;
    if (i < N_NODES) atomicAdd(&counts[seg[i]], 1.0f);
}

// ---------------- head ----------------
__global__ void k_out(const float* __restrict__ pooled, const float* __restrict__ counts,
                      const float* __restrict__ Wout, const float* __restrict__ bout,
                      float* __restrict__ out) {
    __shared__ float prow[D];
    int g = blockIdx.x;
    int t = threadIdx.x;
    if (t < D) prow[t] = pooled[(size_t)g * D + t] / fmaxf(counts[g], 1.0f);
    __syncthreads();
    if (t < N_TARGETS) {
        float acc = bout[t];
#pragma unroll
        for (int k = 0; k < D; ++k)
            acc = fmaf(prow[k], Wout[k * N_TARGETS + t], acc);
        out[g * N_TARGETS + t] = acc;
    }
}

// ---------------- driver ----------------

extern "C" void kernel_launch(void* const* d_in, const int* in_sizes, int n_in,
                              void* d_out, int out_size, void* d_ws, size_t ws_size,
                              hipStream_t stream) {
    const float* x    = (const float*)d_in[0];
    const float* W1   = (const float*)d_in[1];
    const float* b1   = (const float*)d_in[2];
    const float* W2   = (const float*)d_in[3];
    const float* b2   = (const float*)d_in[4];
    const float* W3   = (const float*)d_in[5];
    const float* b3   = (const float*)d_in[6];
    const float* Wout = (const float*)d_in[7];
    const float* bout = (const float*)d_in[8];
    const int*   eidx = (const int*)d_in[9];
    const int*   seg  = (const int*)d_in[10];
    const int* src = eidx;
    const int* dst = eidx + N_EDGES;
    float* out = (float*)d_out;

    // workspace layout (~47 MB)
    _Float16* H16    = (_Float16*)d_ws;                      // 6,400,000 halfs, chunked [4][N][16]
    float*    bufB   = (float*)(H16 + (size_t)N_NODES * D);  // 6,400,000 floats (AGG)
    int*      esrc   = (int*)(bufB + (size_t)N_NODES * D);   // 1,600,000
    float*    dinv   = (float*)(esrc + N_EDGES);             // 100,000
    int*      degc   = (int*)(dinv + N_NODES);               // 100,000
    int*      base   = degc + N_NODES;                       // 100,001 (+pad)
    int*      bsum   = base + N_NODES + 4;                   // 512
    float*    pooled = (float*)(bsum + 512);                 // 32,768
    float*    counts = pooled + N_GRAPHS * D;                // 512

    const int NB = (N_NODES + 255) / 256;  // 391

    // ---- CSR build ----
    k_zero_i<<<NB, 256, 0, stream>>>(degc, N_NODES);
    k_deg<<<N_EDGES / 256, 256, 0, stream>>>(dst, degc);
    k_dinv<<<NB, 256, 0, stream>>>(degc, dinv);
    k_scan1<<<NB, 256, 0, stream>>>(degc, base, bsum);
    k_scan2<<<1, 512, 0, stream>>>(bsum, NB);
    k_scan3<<<NB, 256, 0, stream>>>(base, bsum, degc);
    k_fill<<<N_EDGES / 256, 256, 0, stream>>>(src, dst, base, degc, esrc);

    // ---- 3 GCN layers ----
    const int MMB = (N_NODES + 63) / 64;   // 1563
    const dim3 PG(N_NODES / 16, 4);        // 6250 x 4 chunks
    k_mm<<<MMB, 256, 0, stream>>>(x, W1, dinv, H16, 0);
    k_pull_c<<<PG, 256, 0, stream>>>(H16, esrc, base, dinv, b1, bufB);
    k_mm<<<MMB, 256, 0, stream>>>(bufB, W2, dinv, H16, 1);
    k_pull_c<<<PG, 256, 0, stream>>>(H16, esrc, base, dinv, b2, bufB);
    k_mm<<<MMB, 256, 0, stream>>>(bufB, W3, dinv, H16, 1);
    k_pull_c<<<PG, 256, 0, stream>>>(H16, esrc, base, dinv, b3, bufB);

    // ---- mean pool (sorted-segment) + head ----
    k_zero_f<<<(N_GRAPHS * D + N_GRAPHS + 255) / 256, 256, 0, stream>>>(pooled, N_GRAPHS * D + N_GRAPHS);
    k_counts<<<NB, 256, 0, stream>>>(seg, counts);
    k_pool_seg<<<NB, 256, 0, stream>>>(bufB, seg, pooled);

    k_out<<<N_GRAPHS, 128, 0, stream>>>(pooled, counts, Wout, bout, out);
}